// Round 1
// baseline (4265.763 us; speedup 1.0000x reference)
//
#include <hip/hip_runtime.h>
#include <math.h>

#define NN 33
#define KK 32
#define D  64
#define ED 16
#define EPSV 1e-5f

// One b per block-iteration; wave w owns rows n = w, w+4, ..., lane = output dim.
__global__ __launch_bounds__(256, 4)
void gat_kernel(const float* __restrict__ nodes,
                const float* __restrict__ edges,
                const float* __restrict__ W_w,
                const float* __restrict__ W_b,
                const float* __restrict__ We_w,
                const float* __restrict__ We_b,
                const float* __restrict__ attn_w,
                const float* __restrict__ attn_b,
                const float* __restrict__ gamma,
                const float* __restrict__ beta,
                float* __restrict__ out,
                int B)
{
    __shared__ float s_aw[192];
    __shared__ float s_v2[ED];
    __shared__ float s_scores[KK];
    __shared__ float s_attn[KK];
    __shared__ float s_part[4 * D];
    __shared__ float s_tdot;
    __shared__ float s_const;

    const int tid  = threadIdx.x;
    const int wave = tid >> 6;
    const int lane = tid & 63;

    // Per-lane weight column W[:, lane] — 64 VGPRs, reused for all 8 b's.
    float Wcol[D];
    #pragma unroll
    for (int i = 0; i < D; ++i) Wcol[i] = W_w[i * D + lane];

    const float r_wb    = W_b[lane];
    const float r_gamma = gamma[lane];
    const float r_beta  = beta[lane];
    const float aw0_l   = attn_w[lane];       // target slice of attn_w
    const float aw1_l   = attn_w[D + lane];   // neighbor slice

    if (tid < 192) s_aw[tid] = attn_w[tid];
    __syncthreads();
    // v2 = We_w @ aw2  (16 floats) and const = We_b·aw2 + attn_b — folds the
    // entire (B,32,64) edge matmul into a 16-dot per score.
    if (tid < ED) {
        float v = 0.f;
        #pragma unroll
        for (int o = 0; o < D; ++o) v = fmaf(We_w[tid * D + o], s_aw[128 + o], v);
        s_v2[tid] = v;
    } else if (tid == ED) {
        float c = attn_b[0];
        #pragma unroll
        for (int o = 0; o < D; ++o) c = fmaf(We_b[o], s_aw[128 + o], c);
        s_const = c;
    }
    __syncthreads();

    for (int b = blockIdx.x; b < B; b += gridDim.x) {
        const float* xb = nodes + (size_t)b * (NN * D);

        // ---- h = x @ W + b : each wave computes its rows, lane = out dim ----
        float h[9];
        #pragma unroll
        for (int j = 0; j < 9; ++j) {
            const int n = wave + 4 * j;
            if (n < NN) {
                const float4* xr = (const float4*)(xb + n * D);
                float acc = r_wb;
                #pragma unroll
                for (int q = 0; q < D / 4; ++q) {
                    const float4 x = xr[q];       // wave-uniform broadcast load
                    acc = fmaf(x.x, Wcol[4*q+0], acc);
                    acc = fmaf(x.y, Wcol[4*q+1], acc);
                    acc = fmaf(x.z, Wcol[4*q+2], acc);
                    acc = fmaf(x.w, Wcol[4*q+3], acc);
                }
                h[j] = acc;
            }
        }

        // ---- score partials: s_n = h_n · aw (butterfly reduce across lanes) ----
        #pragma unroll
        for (int j = 0; j < 9; ++j) {
            const int n = wave + 4 * j;
            if (n < NN) {
                float p = h[j] * (n == 0 ? aw0_l : aw1_l);
                #pragma unroll
                for (int s = 1; s < 64; s <<= 1) p += __shfl_xor(p, s, 64);
                if (lane == 0) {
                    if (n == 0) s_tdot = p; else s_scores[n - 1] = p;
                }
            }
        }
        __syncthreads();   // [A] scores/tdot visible

        // ---- softmax over 32 neighbors (wave 0, lanes 0..31) ----
        if (wave == 0 && lane < KK) {
            const float4* eg = (const float4*)(edges + ((size_t)b * KK + lane) * ED);
            float edot = 0.f;
            #pragma unroll
            for (int q = 0; q < ED / 4; ++q) {
                const float4 e = eg[q];
                edot = fmaf(e.x, s_v2[4*q+0], edot);
                edot = fmaf(e.y, s_v2[4*q+1], edot);
                edot = fmaf(e.z, s_v2[4*q+2], edot);
                edot = fmaf(e.w, s_v2[4*q+3], edot);
            }
            const float sk = s_scores[lane] + s_tdot + edot + s_const;
            float m = sk;
            #pragma unroll
            for (int s = 1; s < 32; s <<= 1) m = fmaxf(m, __shfl_xor(m, s, 64));
            const float ex = __expf(sk - m);
            float sum = ex;
            #pragma unroll
            for (int s = 1; s < 32; s <<= 1) sum += __shfl_xor(sum, s, 64);
            s_attn[lane] = ex / sum;
        }
        __syncthreads();   // [B] attn visible

        // ---- messages: per-wave partial sums over owned neighbor rows ----
        float part = 0.f;
        #pragma unroll
        for (int j = 0; j < 9; ++j) {
            const int n = wave + 4 * j;
            if (n >= 1 && n < NN) part = fmaf(s_attn[n - 1], h[j], part);
        }
        s_part[wave * D + lane] = part;
        __syncthreads();   // [C] partials visible

        if (wave == 0) {   // wave 0 owns row 0 (target)
            h[0] += s_part[lane] + s_part[D + lane] + s_part[2 * D + lane] + s_part[3 * D + lane];
        }

        // ---- fused LayerNorm + store ----
        #pragma unroll
        for (int j = 0; j < 9; ++j) {
            const int n = wave + 4 * j;
            if (n < NN) {
                const float x = h[j];
                float s1 = x, s2 = x * x;
                #pragma unroll
                for (int s = 1; s < 64; s <<= 1) {
                    s1 += __shfl_xor(s1, s, 64);
                    s2 += __shfl_xor(s2, s, 64);
                }
                const float mu  = s1 * (1.f / 64.f);
                const float var = s2 * (1.f / 64.f) - mu * mu;
                const float r   = rsqrtf(var + EPSV);
                out[((size_t)b * NN + n) * D + lane] = (x - mu) * r * r_gamma + r_beta;
            }
        }
        // No trailing sync needed: next-iter LDS writes (s_scores at [A'])
        // are ordered after every wave passed [B]/[C] of this iteration.
    }
}

extern "C" void kernel_launch(void* const* d_in, const int* in_sizes, int n_in,
                              void* d_out, int out_size, void* d_ws, size_t ws_size,
                              hipStream_t stream)
{
    const float* nodes  = (const float*)d_in[0];
    const float* edges  = (const float*)d_in[1];
    const float* W_w    = (const float*)d_in[2];
    const float* W_b    = (const float*)d_in[3];
    const float* We_w   = (const float*)d_in[4];
    const float* We_b   = (const float*)d_in[5];
    const float* attn_w = (const float*)d_in[6];
    const float* attn_b = (const float*)d_in[7];
    const float* gamma  = (const float*)d_in[8];
    const float* beta   = (const float*)d_in[9];
    float* out = (float*)d_out;

    const int B = in_sizes[0] / (NN * D);

    dim3 grid(2048), block(256);
    gat_kernel<<<grid, block, 0, stream>>>(nodes, edges, W_w, W_b, We_w, We_b,
                                           attn_w, attn_b, gamma, beta, out, B);
}

// Round 2
// 1725.288 us; speedup vs baseline: 2.4725x; 2.4725x over previous
//
#include <hip/hip_runtime.h>
#include <math.h>

#define NN 33
#define KK 32
#define D  64
#define ED 16
#define EPSV 1e-5f

// W column held in 16 NAMED float4 registers (no local array -> nothing the
// compiler can demote to scratch; round-1 spill cost 30x HBM traffic).
#define FOR16(M) M(0) M(1) M(2) M(3) M(4) M(5) M(6) M(7) \
                 M(8) M(9) M(10) M(11) M(12) M(13) M(14) M(15)

#define W_DECL(q) float4 Wc##q;
#define W_LOAD(q) Wc##q = make_float4(W_w[(4*(q)+0)*D + lane], \
                                      W_w[(4*(q)+1)*D + lane], \
                                      W_w[(4*(q)+2)*D + lane], \
                                      W_w[(4*(q)+3)*D + lane]);
#define W_FMA(q) { const float4 xv = xr[(q)];            \
                   acc = fmaf(xv.x, Wc##q.x, acc);       \
                   acc = fmaf(xv.y, Wc##q.y, acc);       \
                   acc = fmaf(xv.z, Wc##q.z, acc);       \
                   acc = fmaf(xv.w, Wc##q.w, acc); }

// One b per block-iteration; wave w owns rows n = w, w+4, ..., lane = out dim.
__global__ __launch_bounds__(256, 4)
void gat_kernel(const float* __restrict__ nodes,
                const float* __restrict__ edges,
                const float* __restrict__ W_w,
                const float* __restrict__ W_b,
                const float* __restrict__ We_w,
                const float* __restrict__ We_b,
                const float* __restrict__ attn_w,
                const float* __restrict__ attn_b,
                const float* __restrict__ gamma,
                const float* __restrict__ beta,
                float* __restrict__ out,
                int B)
{
    __shared__ float s_aw[192];
    __shared__ float s_v2[ED];
    __shared__ float s_scores[KK];
    __shared__ float s_attn[KK];
    __shared__ float s_part[4 * D];
    __shared__ float s_tdot;
    __shared__ float s_const;

    const int tid  = threadIdx.x;
    const int wave = tid >> 6;
    const int lane = tid & 63;

    // Per-lane weight column W[:, lane] in named registers.
    FOR16(W_DECL)
    FOR16(W_LOAD)

    const float r_wb    = W_b[lane];
    const float r_gamma = gamma[lane];
    const float r_beta  = beta[lane];
    const float aw0_l   = attn_w[lane];       // target slice of attn_w
    const float aw1_l   = attn_w[D + lane];   // neighbor slice

    if (tid < 192) s_aw[tid] = attn_w[tid];
    __syncthreads();
    // v2 = We_w @ aw2 (16 floats) and const = We_b·aw2 + attn_b — folds the
    // entire (B,32,64) edge matmul into a 16-dot per score.
    if (tid < ED) {
        float v = 0.f;
        #pragma unroll
        for (int o = 0; o < D; ++o) v = fmaf(We_w[tid * D + o], s_aw[128 + o], v);
        s_v2[tid] = v;
    } else if (tid == ED) {
        float c = attn_b[0];
        #pragma unroll
        for (int o = 0; o < D; ++o) c = fmaf(We_b[o], s_aw[128 + o], c);
        s_const = c;
    }
    __syncthreads();

    for (int b = blockIdx.x; b < B; b += gridDim.x) {
        const float* xb = nodes + (size_t)b * (NN * D);

        // ---- h = x @ W + b : each wave computes its rows, lane = out dim ----
        float h[9];
        #pragma unroll
        for (int j = 0; j < 9; ++j) {
            const int n = wave + 4 * j;
            if (n < NN) {
                const float4* xr = (const float4*)(xb + n * D);
                float acc = r_wb;
                FOR16(W_FMA)
                h[j] = acc;
            }
        }

        // ---- score partials: s_n = h_n · aw (butterfly reduce across lanes) ----
        #pragma unroll
        for (int j = 0; j < 9; ++j) {
            const int n = wave + 4 * j;
            if (n < NN) {
                float p = h[j] * (n == 0 ? aw0_l : aw1_l);
                #pragma unroll
                for (int s = 1; s < 64; s <<= 1) p += __shfl_xor(p, s, 64);
                if (lane == 0) {
                    if (n == 0) s_tdot = p; else s_scores[n - 1] = p;
                }
            }
        }
        __syncthreads();   // [A] scores/tdot visible

        // ---- softmax over 32 neighbors (wave 0, lanes 0..31) ----
        if (wave == 0 && lane < KK) {
            const float4* eg = (const float4*)(edges + ((size_t)b * KK + lane) * ED);
            float edot = 0.f;
            #pragma unroll
            for (int q = 0; q < ED / 4; ++q) {
                const float4 e = eg[q];
                edot = fmaf(e.x, s_v2[4*q+0], edot);
                edot = fmaf(e.y, s_v2[4*q+1], edot);
                edot = fmaf(e.z, s_v2[4*q+2], edot);
                edot = fmaf(e.w, s_v2[4*q+3], edot);
            }
            const float sk = s_scores[lane] + s_tdot + edot + s_const;
            float m = sk;
            #pragma unroll
            for (int s = 1; s < 32; s <<= 1) m = fmaxf(m, __shfl_xor(m, s, 64));
            const float ex = __expf(sk - m);
            float sum = ex;
            #pragma unroll
            for (int s = 1; s < 32; s <<= 1) sum += __shfl_xor(sum, s, 64);
            s_attn[lane] = ex / sum;
        }
        __syncthreads();   // [B] attn visible

        // ---- messages: per-wave partial sums over owned neighbor rows ----
        float part = 0.f;
        #pragma unroll
        for (int j = 0; j < 9; ++j) {
            const int n = wave + 4 * j;
            if (n >= 1 && n < NN) part = fmaf(s_attn[n - 1], h[j], part);
        }
        s_part[wave * D + lane] = part;
        __syncthreads();   // [C] partials visible

        if (wave == 0) {   // wave 0 owns row 0 (target)
            h[0] += s_part[lane] + s_part[D + lane] + s_part[2 * D + lane] + s_part[3 * D + lane];
        }

        // ---- fused LayerNorm + store ----
        #pragma unroll
        for (int j = 0; j < 9; ++j) {
            const int n = wave + 4 * j;
            if (n < NN) {
                const float x = h[j];
                float s1 = x, s2 = x * x;
                #pragma unroll
                for (int s = 1; s < 64; s <<= 1) {
                    s1 += __shfl_xor(s1, s, 64);
                    s2 += __shfl_xor(s2, s, 64);
                }
                const float mu  = s1 * (1.f / 64.f);
                const float var = s2 * (1.f / 64.f) - mu * mu;
                const float r   = rsqrtf(var + EPSV);
                out[((size_t)b * NN + n) * D + lane] = (x - mu) * r * r_gamma + r_beta;
            }
        }
        // No trailing sync needed: next-iter LDS writes are ordered by [A']/[B']
        // barrier arrival after every wave passed [B]/[C] of this iteration.
    }
}

extern "C" void kernel_launch(void* const* d_in, const int* in_sizes, int n_in,
                              void* d_out, int out_size, void* d_ws, size_t ws_size,
                              hipStream_t stream)
{
    const float* nodes  = (const float*)d_in[0];
    const float* edges  = (const float*)d_in[1];
    const float* W_w    = (const float*)d_in[2];
    const float* W_b    = (const float*)d_in[3];
    const float* We_w   = (const float*)d_in[4];
    const float* We_b   = (const float*)d_in[5];
    const float* attn_w = (const float*)d_in[6];
    const float* attn_b = (const float*)d_in[7];
    const float* gamma  = (const float*)d_in[8];
    const float* beta   = (const float*)d_in[9];
    float* out = (float*)d_out;

    const int B = in_sizes[0] / (NN * D);

    dim3 grid(2048), block(256);
    gat_kernel<<<grid, block, 0, stream>>>(nodes, edges, W_w, W_b, We_w, We_b,
                                           attn_w, attn_b, gamma, beta, out, B);
}

// Round 3
// 821.940 us; speedup vs baseline: 5.1899x; 2.0990x over previous
//
#include <hip/hip_runtime.h>
#include <math.h>

#define NN 33
#define KK 32
#define D  64
#define ED 16
#define EPSV 1e-5f

// W column held in 16 NAMED float4 registers. Round-1/2 lesson: the allocator
// targeted 8 waves/EU (64-VGPR cap) and spilled ~20 of these to scratch
// (183 KB/b extra fetch). amdgpu_waves_per_eu(2,4) sets an occupancy MAX of
// 4 waves/EU -> 128-VGPR budget -> no spill (~110 live VGPRs needed).
#define FOR16(M) M(0) M(1) M(2) M(3) M(4) M(5) M(6) M(7) \
                 M(8) M(9) M(10) M(11) M(12) M(13) M(14) M(15)

#define W_DECL(q) float4 Wc##q;
#define W_LOAD(q) Wc##q = make_float4(W_w[(4*(q)+0)*D + lane], \
                                      W_w[(4*(q)+1)*D + lane], \
                                      W_w[(4*(q)+2)*D + lane], \
                                      W_w[(4*(q)+3)*D + lane]);
#define W_FMA(q) { const float4 xv = xr[(q)];            \
                   acc = fmaf(xv.x, Wc##q.x, acc);       \
                   acc = fmaf(xv.y, Wc##q.y, acc);       \
                   acc = fmaf(xv.z, Wc##q.z, acc);       \
                   acc = fmaf(xv.w, Wc##q.w, acc); }

// One b per block-iteration; wave w owns rows n = w, w+4, ..., lane = out dim.
__global__
__attribute__((amdgpu_flat_work_group_size(256, 256), amdgpu_waves_per_eu(2, 4)))
void gat_kernel(const float* __restrict__ nodes,
                const float* __restrict__ edges,
                const float* __restrict__ W_w,
                const float* __restrict__ W_b,
                const float* __restrict__ We_w,
                const float* __restrict__ We_b,
                const float* __restrict__ attn_w,
                const float* __restrict__ attn_b,
                const float* __restrict__ gamma,
                const float* __restrict__ beta,
                float* __restrict__ out,
                int B)
{
    __shared__ float s_aw[192];
    __shared__ float s_v2[ED];
    __shared__ float s_scores[KK];
    __shared__ float s_attn[KK];
    __shared__ float s_part[4 * D];
    __shared__ float s_tdot;
    __shared__ float s_const;

    const int tid  = threadIdx.x;
    const int wave = tid >> 6;
    const int lane = tid & 63;

    // Per-lane weight column W[:, lane] in named registers.
    FOR16(W_DECL)
    FOR16(W_LOAD)

    const float r_wb    = W_b[lane];
    const float r_gamma = gamma[lane];
    const float r_beta  = beta[lane];
    const float aw0_l   = attn_w[lane];       // target slice of attn_w
    const float aw1_l   = attn_w[D + lane];   // neighbor slice

    if (tid < 192) s_aw[tid] = attn_w[tid];
    __syncthreads();
    // v2 = We_w @ aw2 (16 floats) and const = We_b·aw2 + attn_b — folds the
    // entire (B,32,64) edge matmul into a 16-dot per score.
    if (tid < ED) {
        float v = 0.f;
        #pragma unroll
        for (int o = 0; o < D; ++o) v = fmaf(We_w[tid * D + o], s_aw[128 + o], v);
        s_v2[tid] = v;
    } else if (tid == ED) {
        float c = attn_b[0];
        #pragma unroll
        for (int o = 0; o < D; ++o) c = fmaf(We_b[o], s_aw[128 + o], c);
        s_const = c;
    }
    __syncthreads();

    for (int b = blockIdx.x; b < B; b += gridDim.x) {
        const float* xb = nodes + (size_t)b * (NN * D);

        // ---- h = x @ W + b : each wave computes its rows, lane = out dim ----
        float h[9];
        #pragma unroll
        for (int j = 0; j < 9; ++j) {
            const int n = wave + 4 * j;
            if (n < NN) {
                const float4* xr = (const float4*)(xb + n * D);
                float acc = r_wb;
                FOR16(W_FMA)
                h[j] = acc;
            }
        }

        // ---- score partials: s_n = h_n · aw (butterfly reduce across lanes) ----
        #pragma unroll
        for (int j = 0; j < 9; ++j) {
            const int n = wave + 4 * j;
            if (n < NN) {
                float p = h[j] * (n == 0 ? aw0_l : aw1_l);
                #pragma unroll
                for (int s = 1; s < 64; s <<= 1) p += __shfl_xor(p, s, 64);
                if (lane == 0) {
                    if (n == 0) s_tdot = p; else s_scores[n - 1] = p;
                }
            }
        }
        __syncthreads();   // [A] scores/tdot visible

        // ---- softmax over 32 neighbors (wave 0, lanes 0..31) ----
        if (wave == 0 && lane < KK) {
            const float4* eg = (const float4*)(edges + ((size_t)b * KK + lane) * ED);
            float edot = 0.f;
            #pragma unroll
            for (int q = 0; q < ED / 4; ++q) {
                const float4 e = eg[q];
                edot = fmaf(e.x, s_v2[4*q+0], edot);
                edot = fmaf(e.y, s_v2[4*q+1], edot);
                edot = fmaf(e.z, s_v2[4*q+2], edot);
                edot = fmaf(e.w, s_v2[4*q+3], edot);
            }
            const float sk = s_scores[lane] + s_tdot + edot + s_const;
            float m = sk;
            #pragma unroll
            for (int s = 1; s < 32; s <<= 1) m = fmaxf(m, __shfl_xor(m, s, 64));
            const float ex = __expf(sk - m);
            float sum = ex;
            #pragma unroll
            for (int s = 1; s < 32; s <<= 1) sum += __shfl_xor(sum, s, 64);
            s_attn[lane] = ex / sum;
        }
        __syncthreads();   // [B] attn visible

        // ---- messages: per-wave partial sums over owned neighbor rows ----
        float part = 0.f;
        #pragma unroll
        for (int j = 0; j < 9; ++j) {
            const int n = wave + 4 * j;
            if (n >= 1 && n < NN) part = fmaf(s_attn[n - 1], h[j], part);
        }
        s_part[wave * D + lane] = part;
        __syncthreads();   // [C] partials visible

        if (wave == 0) {   // wave 0 owns row 0 (target)
            h[0] += s_part[lane] + s_part[D + lane] + s_part[2 * D + lane] + s_part[3 * D + lane];
        }

        // ---- fused LayerNorm + store ----
        #pragma unroll
        for (int j = 0; j < 9; ++j) {
            const int n = wave + 4 * j;
            if (n < NN) {
                const float x = h[j];
                float s1 = x, s2 = x * x;
                #pragma unroll
                for (int s = 1; s < 64; s <<= 1) {
                    s1 += __shfl_xor(s1, s, 64);
                    s2 += __shfl_xor(s2, s, 64);
                }
                const float mu  = s1 * (1.f / 64.f);
                const float var = s2 * (1.f / 64.f) - mu * mu;
                const float r   = rsqrtf(var + EPSV);
                out[((size_t)b * NN + n) * D + lane] = (x - mu) * r * r_gamma + r_beta;
            }
        }
        // No trailing sync needed: next-iter LDS writes are ordered by the
        // [A']/[B'] barriers after every wave passed [B]/[C] of this iteration.
    }
}

extern "C" void kernel_launch(void* const* d_in, const int* in_sizes, int n_in,
                              void* d_out, int out_size, void* d_ws, size_t ws_size,
                              hipStream_t stream)
{
    const float* nodes  = (const float*)d_in[0];
    const float* edges  = (const float*)d_in[1];
    const float* W_w    = (const float*)d_in[2];
    const float* W_b    = (const float*)d_in[3];
    const float* We_w   = (const float*)d_in[4];
    const float* We_b   = (const float*)d_in[5];
    const float* attn_w = (const float*)d_in[6];
    const float* attn_b = (const float*)d_in[7];
    const float* gamma  = (const float*)d_in[8];
    const float* beta   = (const float*)d_in[9];
    float* out = (float*)d_out;

    const int B = in_sizes[0] / (NN * D);

    dim3 grid(2048), block(256);
    gat_kernel<<<grid, block, 0, stream>>>(nodes, edges, W_w, W_b, We_w, We_b,
                                           attn_w, attn_b, gamma, beta, out, B);
}